// Round 3
// baseline (144.970 us; speedup 1.0000x reference)
//
#include <hip/hip_runtime.h>
#include <hip/hip_bf16.h>

#define EPSF 1e-7f
#define B_ 8
#define H_ 64
#define W_ 64
#define C_ 32
#define HO 58
#define WO 58
#define NF 64
#define KDIM 800

#define XTS 36      // xt padded channel stride (floats): 16B-aligned, bank spread
#define RPS 520     // rot pos-stride in bf16 units (16*32 + 8): 16B-aligned, bank spread

typedef __bf16 v8bf __attribute__((ext_vector_type(8)));
typedef float  v4f  __attribute__((ext_vector_type(4)));

// ---- fully fused: stage -> intensity -> angle -> rotate -> MFMA ----
// W fragments loaded straight from global (L2-resident), fp32->bf16 in-register.
__global__ __launch_bounds__(256)
void k_main(const float* __restrict__ x, const float* __restrict__ W,
            const float* __restrict__ bias, float* __restrict__ out) {
    __shared__ float  xt[7][22][XTS];     // 22,176 B
    __shared__ __bf16 rot[25*RPS];        // 26,000 B
    __shared__ float  Srow[7][22];
    __shared__ float4 pp[16];

    int tid = threadIdx.x;
    int wv = tid >> 6, lane = tid & 63;
    int wt = blockIdx.x, ho = blockIdx.y, b = blockIdx.z;
    int wo0 = wt*16;
    int npx = WO - wo0; if (npx > 16) npx = 16;   // 16,16,16,10
    int ncols = npx + 6;

    // hoisted B-fragment loads from global W: f = wv*16+(lane&15), k = kb*32+(lane>>4)*8+j
    int m = lane & 15, q = lane >> 4;
    v8bf bfrag[25];
    {
        const float* wsrc = W + (size_t)(wv*16 + m)*KDIM + q*8;
#pragma unroll
        for (int kb = 0; kb < 25; kb++) {
            float4 w0 = *(const float4*)(wsrc + kb*32);
            float4 w1 = *(const float4*)(wsrc + kb*32 + 4);
            v8bf f;
            f[0]=(__bf16)w0.x; f[1]=(__bf16)w0.y; f[2]=(__bf16)w0.z; f[3]=(__bf16)w0.w;
            f[4]=(__bf16)w1.x; f[5]=(__bf16)w1.y; f[6]=(__bf16)w1.z; f[7]=(__bf16)w1.w;
            bfrag[kb] = f;
        }
    }

    // phase 0: stage x tile (rows ho..ho+6, cols wo0..wo0+ncols-1, 32 ch)
    const float* xb = x + (size_t)((b*H_ + ho)*W_ + wo0)*C_;
    int total4 = 7*ncols*8;
    for (int e = tid; e < total4; e += 256) {
        int r = e/(ncols*8); int rem = e - r*(ncols*8);
        int c = rem >> 3;    int qq = rem & 7;
        *(float4*)&xt[r][c][qq*4] = *(const float4*)&xb[(r*W_ + c)*C_ + qq*4];
    }
    __syncthreads();

    // phase 1: per-(row,col) channel sums
    if (tid < 7*ncols) {
        int r = tid / ncols, c = tid - r*ncols;
        float s = 0.f;
#pragma unroll
        for (int qq = 0; qq < 8; qq++) {
            float4 v = *(const float4*)&xt[r][c][qq*4];
            s += v.x + v.y + v.z + v.w;
        }
        Srow[r][c] = s;
    }
    __syncthreads();

    // phase 2: per-pixel affine params
    if (tid < npx) {
        float den = 0.f, crn = 0.f, ccn = 0.f;
#pragma unroll
        for (int i = 0; i < 7; i++)
#pragma unroll
            for (int j = 0; j < 7; j++) {
                float v = Srow[i][tid + j];
                den += v; crn += v*(float)i; ccn += v*(float)j;
            }
        float dt = den + EPSF;
        float cr = crn/dt - 3.0f;
        float cc = ccn/dt - 3.0f;
        float ang = atan2f(cr, cc + EPSF);
        float c = cosf(ang), s = sinf(ang);
        const float scale = 1.0f + EPSF;
        float xo = (6.0f - (c*6.0f - s*6.0f))*0.5f;
        float yo = (6.0f - (s*6.0f + c*6.0f))*0.5f;
        pp[tid] = make_float4(c/scale, s/scale, xo/scale, yo/scale);
    }
    __syncthreads();

    // phase 3: one thread per (px,pos), all 32 channels; affine computed once
    int tot = npx*25;
    for (int e = tid; e < tot; e += 256) {
        int px = e/25; int pos = e - px*25;
        int py = pos/5; int yy = py + 1; int xx = pos - py*5 + 1;
        float4 p = pp[px];
        float xin = p.x*(float)xx - p.y*(float)yy + p.z;
        float yin = p.y*(float)xx + p.x*(float)yy + p.w;
        float x0f = floorf(xin), y0f = floorf(yin);
        float wx1 = xin - x0f, wx0 = 1.0f - wx1;
        float wy1 = yin - y0f, wy0 = 1.0f - wy1;
        int ix0 = (int)x0f, iy0 = (int)y0f;
        int ix1 = ix0 + 1,  iy1 = iy0 + 1;

        const float* bp[4]; float wgt[4];
        auto mkcorner = [&](int yi, int xi, float w, int idx) {
            bool valid = (xi >= 0) & (xi < 7) & (yi >= 0) & (yi < 7);
            int cy = yi < 0 ? 0 : (yi > 6 ? 6 : yi);
            int cx = xi < 0 ? 0 : (xi > 6 ? 6 : xi);
            bp[idx]  = &xt[cy][px + cx][0];
            wgt[idx] = valid ? w : 0.0f;
        };
        mkcorner(iy0, ix0, wy0*wx0, 0);
        mkcorner(iy0, ix1, wy0*wx1, 1);
        mkcorner(iy1, ix0, wy1*wx0, 2);
        mkcorner(iy1, ix1, wy1*wx1, 3);

        float acc[32];
#pragma unroll
        for (int ch = 0; ch < 32; ch++) acc[ch] = 0.f;
#pragma unroll
        for (int cn = 0; cn < 4; cn++) {
            const float* src = bp[cn]; float wq = wgt[cn];
#pragma unroll
            for (int qq = 0; qq < 8; qq++) {
                float4 v = *(const float4*)(src + qq*4);
                acc[qq*4+0] += wq*v.x; acc[qq*4+1] += wq*v.y;
                acc[qq*4+2] += wq*v.z; acc[qq*4+3] += wq*v.w;
            }
        }
        __bf16* dst = &rot[pos*RPS + px*32];
#pragma unroll
        for (int q8 = 0; q8 < 4; q8++) {
            v8bf o;
#pragma unroll
            for (int j = 0; j < 8; j++) o[j] = (__bf16)acc[q8*8 + j];
            *(v8bf*)&dst[q8*8] = o;
        }
    }
    __syncthreads();

    // phase 4: MFMA, 16 px x 16 filters per wave, K=800
    v4f acc4 = {0.f, 0.f, 0.f, 0.f};
#pragma unroll
    for (int kb = 0; kb < 25; kb++) {
        v8bf a = *(const v8bf*)&rot[kb*RPS + m*32 + q*8];
        acc4 = __builtin_amdgcn_mfma_f32_16x16x32_bf16(a, bfrag[kb], acc4, 0, 0, 0);
    }
    int f = wv*16 + m;          // C/D col = lane&15 -> filter
    float bv = bias[f];
    int pixbase = (b*HO + ho)*WO + wo0;
#pragma unroll
    for (int r = 0; r < 4; r++) {
        int px = q*4 + r;       // C/D row = (lane>>4)*4 + reg -> pixel
        if (px < npx) out[(size_t)(pixbase + px)*NF + f] = acc4[r] + bv;
    }
}

extern "C" void kernel_launch(void* const* d_in, const int* in_sizes, int n_in,
                              void* d_out, int out_size, void* d_ws, size_t ws_size,
                              hipStream_t stream) {
    const float* x    = (const float*)d_in[0];
    const float* W    = (const float*)d_in[1];
    const float* bias = (const float*)d_in[2];
    float* out = (float*)d_out;
    k_main<<<dim3(4, HO, B_), 256, 0, stream>>>(x, W, bias, out);
}

// Round 4
// 83.458 us; speedup vs baseline: 1.7370x; 1.7370x over previous
//
#include <hip/hip_runtime.h>
#include <hip/hip_bf16.h>

#define EPSF 1e-7f
#define B_ 8
#define H_ 64
#define W_ 64
#define C_ 32
#define HO 58
#define WO 58
#define NF 64
#define KDIM 800

#define XTS 36      // xt channel stride (floats): 16B-aligned, banks +4 per col
#define RS  808     // rot row stride (bf16): (RS/2)%32 = 20 -> conflict-free b128 r/w

typedef __bf16 v8bf __attribute__((ext_vector_type(8)));
typedef float  v4f  __attribute__((ext_vector_type(4)));

// ---- pack W into MFMA B-fragment order, bf16 ----
// Wp[((nt*25+kb)*64+lane)*8+j] = W[f=nt*16+(lane&15)][k=kb*32+(lane>>4)*8+j]
__global__ void k_wpack(const float* __restrict__ W, __bf16* __restrict__ Wp) {
    int t = blockIdx.x*256 + threadIdx.x;   // 51200 total
    int j = t & 7; int lane = (t >> 3) & 63; int rest = t >> 9;
    int kb = rest % 25; int nt = rest / 25;
    int f = nt*16 + (lane & 15);
    int k = kb*32 + (lane >> 4)*8 + j;
    Wp[t] = (__bf16)W[f*KDIM + k];
}

// ---- fused: stage -> intensity -> angle(no trig) -> rotate -> MFMA ----
__global__ __launch_bounds__(256)
void k_main(const float* __restrict__ x, const v8bf* __restrict__ Wp,
            const float* __restrict__ bias, float* __restrict__ out) {
    __shared__ float  xt[7][22][XTS];     // 22,176 B
    __shared__ __bf16 rot[16][RS];        // 25,856 B
    __shared__ float  Srow[7][22];        //    616 B
    __shared__ float4 pp[16];             //    256 B   -> 48,904 B total

    int tid = threadIdx.x;
    int wv = tid >> 6, lane = tid & 63;
    int m = lane & 15, q = lane >> 4;
    int wt = blockIdx.x, ho = blockIdx.y, b = blockIdx.z;
    int wo0 = wt*16;
    int npx = WO - wo0; if (npx > 16) npx = 16;   // 16,16,16,10
    int ncols = npx + 6;

    // phase 0: stage x tile (rows ho..ho+6, cols wo0..wo0+ncols-1, 32 ch)
    const float* xb = x + (size_t)((b*H_ + ho)*W_ + wo0)*C_;
    int total4 = 7*ncols*8;
    for (int e = tid; e < total4; e += 256) {
        int r = e/(ncols*8); int rem = e - r*(ncols*8);
        int c = rem >> 3;    int qq = rem & 7;
        *(float4*)&xt[r][c][qq*4] = *(const float4*)&xb[(r*W_ + c)*C_ + qq*4];
    }
    __syncthreads();

    // phase 1: per-(row,col) channel sums
    if (tid < 7*ncols) {
        int r = tid / ncols, c = tid - r*ncols;
        float s = 0.f;
#pragma unroll
        for (int qq = 0; qq < 8; qq++) {
            float4 v = *(const float4*)&xt[r][c][qq*4];
            s += v.x + v.y + v.z + v.w;
        }
        Srow[r][c] = s;
    }
    __syncthreads();

    // phase 2: per-pixel affine params; cos/sin via x/r, y/r (no trig)
    if (tid < npx) {
        float den = 0.f, crn = 0.f, ccn = 0.f;
#pragma unroll
        for (int i = 0; i < 7; i++)
#pragma unroll
            for (int j = 0; j < 7; j++) {
                float v = Srow[i][tid + j];
                den += v; crn += v*(float)i; ccn += v*(float)j;
            }
        float dt = den + EPSF;
        float cr = crn/dt - 3.0f;
        float cx = ccn/dt - 3.0f + EPSF;
        float r2 = cr*cr + cx*cx;
        float inv = r2 > 0.f ? rsqrtf(r2) : 0.f;
        float c = r2 > 0.f ? cx*inv : 1.0f;
        float s = cr*inv;
        const float scale = 1.0f + EPSF;
        float xo = (6.0f - (c*6.0f - s*6.0f))*0.5f;
        float yo = (6.0f - (s*6.0f + c*6.0f))*0.5f;
        pp[tid] = make_float4(c/scale, s/scale, xo/scale, yo/scale);
    }
    __syncthreads();

    // phase 3: one thread per (px,pos); px fastest so b128 writes spread banks
    for (int e = tid; e < 400; e += 256) {
        int px = e & 15; int pos = e >> 4;
        if (px < npx) {
            int py = pos/5; int yy = py + 1; int xx = pos - py*5 + 1;
            float4 p = pp[px];
            float xin = p.x*(float)xx - p.y*(float)yy + p.z;
            float yin = p.y*(float)xx + p.x*(float)yy + p.w;
            float x0f = floorf(xin), y0f = floorf(yin);
            float wx1 = xin - x0f, wx0 = 1.0f - wx1;
            float wy1 = yin - y0f, wy0 = 1.0f - wy1;
            int ix0 = (int)x0f, iy0 = (int)y0f;
            int ix1 = ix0 + 1,  iy1 = iy0 + 1;

            const float* bp[4]; float wgt[4];
            auto mkcorner = [&](int yi, int xi, float w, int idx) {
                bool valid = (xi >= 0) & (xi < 7) & (yi >= 0) & (yi < 7);
                int cy = yi < 0 ? 0 : (yi > 6 ? 6 : yi);
                int cx2 = xi < 0 ? 0 : (xi > 6 ? 6 : xi);
                bp[idx]  = &xt[cy][px + cx2][0];
                wgt[idx] = valid ? w : 0.0f;
            };
            mkcorner(iy0, ix0, wy0*wx0, 0);
            mkcorner(iy0, ix1, wy0*wx1, 1);
            mkcorner(iy1, ix0, wy1*wx0, 2);
            mkcorner(iy1, ix1, wy1*wx1, 3);

            float acc[32];
#pragma unroll
            for (int ch = 0; ch < 32; ch++) acc[ch] = 0.f;
#pragma unroll
            for (int cn = 0; cn < 4; cn++) {
                const float* src = bp[cn]; float wq = wgt[cn];
#pragma unroll
                for (int qq = 0; qq < 8; qq++) {
                    float4 v = *(const float4*)(src + qq*4);
                    acc[qq*4+0] += wq*v.x; acc[qq*4+1] += wq*v.y;
                    acc[qq*4+2] += wq*v.z; acc[qq*4+3] += wq*v.w;
                }
            }
            __bf16* dst = &rot[px][pos*32];
#pragma unroll
            for (int q8 = 0; q8 < 4; q8++) {
                v8bf o;
#pragma unroll
                for (int j = 0; j < 8; j++) o[j] = (__bf16)acc[q8*8 + j];
                *(v8bf*)&dst[q8*8] = o;
            }
        }
    }

    // coalesced B-fragment loads (L2-hot Wp); latency hides under the barrier
    v8bf bfrag[25];
    {
        const v8bf* wp = Wp + (size_t)wv*25*64 + lane;
#pragma unroll
        for (int kb = 0; kb < 25; kb++) bfrag[kb] = wp[kb*64];
    }
    __syncthreads();

    // phase 4: MFMA, 16 px x 16 filters per wave, K=800
    v4f acc4 = {0.f, 0.f, 0.f, 0.f};
#pragma unroll
    for (int kb = 0; kb < 25; kb++) {
        v8bf a = *(const v8bf*)&rot[m][kb*32 + q*8];
        acc4 = __builtin_amdgcn_mfma_f32_16x16x32_bf16(a, bfrag[kb], acc4, 0, 0, 0);
    }
    int f = wv*16 + m;          // C/D col = lane&15 -> filter
    float bv = bias[f];
    int pixbase = (b*HO + ho)*WO + wo0;
#pragma unroll
    for (int r = 0; r < 4; r++) {
        int px = q*4 + r;       // C/D row = (lane>>4)*4 + reg -> pixel
        if (px < npx) out[(size_t)(pixbase + px)*NF + f] = acc4[r] + bv;
    }
}

extern "C" void kernel_launch(void* const* d_in, const int* in_sizes, int n_in,
                              void* d_out, int out_size, void* d_ws, size_t ws_size,
                              hipStream_t stream) {
    const float* x    = (const float*)d_in[0];
    const float* W    = (const float*)d_in[1];
    const float* bias = (const float*)d_in[2];
    float* out = (float*)d_out;
    __bf16* Wp = (__bf16*)d_ws;                    // 102,400 B

    k_wpack<<<dim3(200), 256, 0, stream>>>(W, Wp);
    k_main<<<dim3(4, HO, B_), 256, 0, stream>>>(x, (const v8bf*)Wp, bias, out);
}

// Round 5
// 78.877 us; speedup vs baseline: 1.8379x; 1.0581x over previous
//
#include <hip/hip_runtime.h>
#include <hip/hip_bf16.h>

#define EPSF 1e-7f
#define B_ 8
#define H_ 64
#define W_ 64
#define C_ 32
#define HO 58
#define WO 58
#define NF 64
#define KDIM 800

#define XBS 40      // xtb col stride (bf16): 80B -> +20 banks per col, b128-aligned
#define RS  808     // rot row stride (bf16): 1616B -> +20 banks per row, conflict-free

typedef __bf16 v8bf __attribute__((ext_vector_type(8)));
typedef float  v4f  __attribute__((ext_vector_type(4)));

// ---- pack W into MFMA B-fragment order, bf16 ----
// Wp[((nt*25+kb)*64+lane)*8+j] = W[f=nt*16+(lane&15)][k=kb*32+(lane>>4)*8+j]
__global__ void k_wpack(const float* __restrict__ W, __bf16* __restrict__ Wp) {
    int t = blockIdx.x*256 + threadIdx.x;   // 51200 total
    int j = t & 7; int lane = (t >> 3) & 63; int rest = t >> 9;
    int kb = rest % 25; int nt = rest / 25;
    int f = nt*16 + (lane & 15);
    int k = kb*32 + (lane >> 4)*8 + j;
    Wp[t] = (__bf16)W[f*KDIM + k];
}

// ---- fused: stage(bf16)+chansum -> angle -> rotate -> MFMA ----
__global__ __launch_bounds__(256, 4)
void k_main(const float* __restrict__ x, const v8bf* __restrict__ Wp,
            const float* __restrict__ bias, float* __restrict__ out) {
    __shared__ __bf16 xtb[7][22][XBS];    // 12,320 B
    __shared__ __bf16 rot[16][RS];        // 25,856 B
    __shared__ float  Srow[7][22];        //    616 B
    __shared__ float4 pp[16];             //    256 B  -> ~39 KB

    int tid = threadIdx.x;
    int wv = tid >> 6, lane = tid & 63;
    int m = lane & 15, q = lane >> 4;
    int wt = blockIdx.x, ho = blockIdx.y, b = blockIdx.z;
    int wo0 = wt*16;
    int npx = WO - wo0; if (npx > 16) npx = 16;   // 16,16,16,10
    int ncols = npx + 6;                          // 22 or 16

    float bv = bias[wv*16 + m];                   // hoisted off the tail

    // phase 0+1: one thread per (r,c): load 32 fp32 ch, exact fp32 sum -> Srow,
    // bf16 round -> xtb. One barrier covers both.
    if (tid < 7*ncols) {
        int r, c;
        if (ncols == 22) { r = tid/22; c = tid - r*22; }
        else             { r = tid >> 4; c = tid & 15; }
        const float* src = x + (size_t)((b*H_ + ho + r)*W_ + wo0 + c)*C_;
        float4 vq[8];
#pragma unroll
        for (int qq = 0; qq < 8; qq++) vq[qq] = *(const float4*)(src + qq*4);
        float s = 0.f;
#pragma unroll
        for (int qq = 0; qq < 8; qq++) s += vq[qq].x + vq[qq].y + vq[qq].z + vq[qq].w;
        Srow[r][c] = s;
#pragma unroll
        for (int h8 = 0; h8 < 4; h8++) {
            v8bf o;
            o[0]=(__bf16)vq[h8*2].x;   o[1]=(__bf16)vq[h8*2].y;
            o[2]=(__bf16)vq[h8*2].z;   o[3]=(__bf16)vq[h8*2].w;
            o[4]=(__bf16)vq[h8*2+1].x; o[5]=(__bf16)vq[h8*2+1].y;
            o[6]=(__bf16)vq[h8*2+1].z; o[7]=(__bf16)vq[h8*2+1].w;
            *(v8bf*)&xtb[r][c][h8*8] = o;
        }
    }
    __syncthreads();

    // phase 2: per-pixel affine params (fp32-exact Srow; cos/sin via rsqrt)
    if (tid < npx) {
        float den = 0.f, crn = 0.f, ccn = 0.f;
#pragma unroll
        for (int i = 0; i < 7; i++)
#pragma unroll
            for (int j = 0; j < 7; j++) {
                float v = Srow[i][tid + j];
                den += v; crn += v*(float)i; ccn += v*(float)j;
            }
        float dt = den + EPSF;
        float cr = crn/dt - 3.0f;
        float cx = ccn/dt - 3.0f + EPSF;
        float r2 = cr*cr + cx*cx;
        float inv = r2 > 0.f ? rsqrtf(r2) : 0.f;
        float c = r2 > 0.f ? cx*inv : 1.0f;
        float s = cr*inv;
        const float scale = 1.0f + EPSF;
        float xo = (6.0f - (c*6.0f - s*6.0f))*0.5f;
        float yo = (6.0f - (s*6.0f + c*6.0f))*0.5f;
        pp[tid] = make_float4(c/scale, s/scale, xo/scale, yo/scale);
    }
    __syncthreads();

    // phase 3: one thread per (px,pos); 16 b128 LDS reads/item (bf16 corners)
    for (int e = tid; e < 400; e += 256) {
        int px = e & 15; int pos = e >> 4;
        if (px < npx) {
            int py = pos/5; int yy = py + 1; int xx = pos - py*5 + 1;
            float4 p = pp[px];
            float xin = p.x*(float)xx - p.y*(float)yy + p.z;
            float yin = p.y*(float)xx + p.x*(float)yy + p.w;
            float x0f = floorf(xin), y0f = floorf(yin);
            float wx1 = xin - x0f, wx0 = 1.0f - wx1;
            float wy1 = yin - y0f, wy0 = 1.0f - wy1;
            int ix0 = (int)x0f, iy0 = (int)y0f;
            int ix1 = ix0 + 1,  iy1 = iy0 + 1;

            const __bf16* bp[4]; float wgt[4];
            auto mkcorner = [&](int yi, int xi, float w, int idx) {
                bool valid = (xi >= 0) & (xi < 7) & (yi >= 0) & (yi < 7);
                int cy = yi < 0 ? 0 : (yi > 6 ? 6 : yi);
                int cx2 = xi < 0 ? 0 : (xi > 6 ? 6 : xi);
                bp[idx]  = &xtb[cy][px + cx2][0];
                wgt[idx] = valid ? w : 0.0f;
            };
            mkcorner(iy0, ix0, wy0*wx0, 0);
            mkcorner(iy0, ix1, wy0*wx1, 1);
            mkcorner(iy1, ix0, wy1*wx0, 2);
            mkcorner(iy1, ix1, wy1*wx1, 3);

            float accx[16], accy[16];   // ch pairs (2i, 2i+1)
#pragma unroll
            for (int i = 0; i < 16; i++) { accx[i] = 0.f; accy[i] = 0.f; }
#pragma unroll
            for (int cn = 0; cn < 4; cn++) {
                const __bf16* src = bp[cn]; float wq = wgt[cn];
#pragma unroll
                for (int q8 = 0; q8 < 4; q8++) {
                    union { v8bf v; unsigned u[4]; } uv;
                    uv.v = *(const v8bf*)(src + q8*8);
#pragma unroll
                    for (int j = 0; j < 4; j++) {
                        float lo = __uint_as_float(uv.u[j] << 16);
                        float hi = __uint_as_float(uv.u[j] & 0xffff0000u);
                        accx[q8*4+j] += wq*lo;
                        accy[q8*4+j] += wq*hi;
                    }
                }
            }
            __bf16* dst = &rot[px][pos*32];
#pragma unroll
            for (int q8 = 0; q8 < 4; q8++) {
                v8bf o;
#pragma unroll
                for (int j = 0; j < 4; j++) {
                    o[2*j]   = (__bf16)accx[q8*4+j];
                    o[2*j+1] = (__bf16)accy[q8*4+j];
                }
                *(v8bf*)&rot[px][pos*32 + q8*8] = o;
            }
            (void)dst;
        }
    }

    // first half of B-fragments: issue before barrier, latency hides under it
    const v8bf* wp = Wp + (size_t)wv*25*64 + lane;
    v8bf bfA[13];
#pragma unroll
    for (int kb = 0; kb < 13; kb++) bfA[kb] = wp[kb*64];
    __syncthreads();

    // phase 4: MFMA 16 px x 16 filters per wave, K=800
    v4f acc4 = {0.f, 0.f, 0.f, 0.f};
    v8bf bfB[12];
#pragma unroll
    for (int kb = 0; kb < 12; kb++) bfB[kb] = wp[(13 + kb)*64];
#pragma unroll
    for (int kb = 0; kb < 13; kb++) {
        v8bf a = *(const v8bf*)&rot[m][kb*32 + q*8];
        acc4 = __builtin_amdgcn_mfma_f32_16x16x32_bf16(a, bfA[kb], acc4, 0, 0, 0);
    }
#pragma unroll
    for (int kb = 0; kb < 12; kb++) {
        v8bf a = *(const v8bf*)&rot[m][(13 + kb)*32 + q*8];
        acc4 = __builtin_amdgcn_mfma_f32_16x16x32_bf16(a, bfB[kb], acc4, 0, 0, 0);
    }
    int f = wv*16 + m;          // C/D col = lane&15 -> filter
    int pixbase = (b*HO + ho)*WO + wo0;
#pragma unroll
    for (int r = 0; r < 4; r++) {
        int px = q*4 + r;       // C/D row = (lane>>4)*4 + reg -> pixel
        if (px < npx) out[(size_t)(pixbase + px)*NF + f] = acc4[r] + bv;
    }
}

extern "C" void kernel_launch(void* const* d_in, const int* in_sizes, int n_in,
                              void* d_out, int out_size, void* d_ws, size_t ws_size,
                              hipStream_t stream) {
    const float* x    = (const float*)d_in[0];
    const float* W    = (const float*)d_in[1];
    const float* bias = (const float*)d_in[2];
    float* out = (float*)d_out;
    __bf16* Wp = (__bf16*)d_ws;                    // 102,400 B

    k_wpack<<<dim3(200), 256, 0, stream>>>(W, Wp);
    k_main<<<dim3(4, HO, B_), 256, 0, stream>>>(x, (const v8bf*)Wp, bias, out);
}

// Round 6
// 78.302 us; speedup vs baseline: 1.8514x; 1.0073x over previous
//
#include <hip/hip_runtime.h>
#include <hip/hip_bf16.h>

#define EPSF 1e-7f
#define B_ 8
#define H_ 64
#define W_ 64
#define C_ 32
#define HO 58
#define WO 58
#define NF 64
#define KDIM 800

#define XBS 40      // xtb col stride (bf16): 80B -> +20 banks per col, b128-aligned
#define RS  808     // rot row stride (bf16): 1616B -> +20 banks per row, 2-way max (free)

typedef __bf16 v8bf __attribute__((ext_vector_type(8)));
typedef float  v4f  __attribute__((ext_vector_type(4)));

// ---- pack W into MFMA B-fragment order, bf16 ----
// Wp[((nt*25+kb)*64+lane)*8+j] = W[f=nt*16+(lane&15)][k=kb*32+(lane>>4)*8+j]
__global__ void k_wpack(const float* __restrict__ W, __bf16* __restrict__ Wp) {
    int t = blockIdx.x*256 + threadIdx.x;   // 51200 total
    int j = t & 7; int lane = (t >> 3) & 63; int rest = t >> 9;
    int kb = rest % 25; int nt = rest / 25;
    int f = nt*16 + (lane & 15);
    int k = kb*32 + (lane >> 4)*8 + j;
    Wp[t] = (__bf16)W[f*KDIM + k];
}

// ---- fused: stage(bf16)+chansum -> angle -> rotate -> MFMA ----
__global__ __launch_bounds__(256, 4)
void k_main(const float* __restrict__ x, const v8bf* __restrict__ Wp,
            const float* __restrict__ bias, float* __restrict__ out) {
    __shared__ __bf16 xtb[7][22][XBS];    // 12,320 B
    __shared__ __bf16 rot[16][RS];        // 25,856 B
    __shared__ float  Srow[7][22];        //    616 B
    __shared__ float4 pp[16];             //    256 B  -> ~39 KB

    int tid = threadIdx.x;
    int wv = tid >> 6, lane = tid & 63;
    int m = lane & 15, q = lane >> 4;

    // XCD-aware remap: default dispatch round-robins linear id over 8 XCDs.
    // newL = (L&7)*232 + (L>>3) gives each XCD one batch b (x-slice 524 KB
    // -> L2-resident; Wp 100 KB L2-hot). Pure perf heuristic, any mapping ok.
    {
    }
    int L = blockIdx.x + 4*(blockIdx.y + 58*blockIdx.z);
    int newL = (L & 7)*232 + (L >> 3);
    int b  = newL / 232;
    int rem = newL - b*232;
    int ho = rem >> 2;
    int wt = rem & 3;

    int wo0 = wt*16;
    int npx = WO - wo0; if (npx > 16) npx = 16;   // 16,16,16,10
    int ncols = npx + 6;                          // 22 or 16

    float bv = bias[wv*16 + m];                   // hoisted off the tail

    // phase 0+1: one thread per (r,c): load 32 fp32 ch, exact fp32 sum -> Srow,
    // bf16 round -> xtb. One barrier covers both.
    if (tid < 7*ncols) {
        int r, c;
        if (ncols == 22) { r = tid/22; c = tid - r*22; }
        else             { r = tid >> 4; c = tid & 15; }
        const float* src = x + (size_t)((b*H_ + ho + r)*W_ + wo0 + c)*C_;
        float4 vq[8];
#pragma unroll
        for (int qq = 0; qq < 8; qq++) vq[qq] = *(const float4*)(src + qq*4);
        float s = 0.f;
#pragma unroll
        for (int qq = 0; qq < 8; qq++) s += vq[qq].x + vq[qq].y + vq[qq].z + vq[qq].w;
        Srow[r][c] = s;
#pragma unroll
        for (int h8 = 0; h8 < 4; h8++) {
            v8bf o;
            o[0]=(__bf16)vq[h8*2].x;   o[1]=(__bf16)vq[h8*2].y;
            o[2]=(__bf16)vq[h8*2].z;   o[3]=(__bf16)vq[h8*2].w;
            o[4]=(__bf16)vq[h8*2+1].x; o[5]=(__bf16)vq[h8*2+1].y;
            o[6]=(__bf16)vq[h8*2+1].z; o[7]=(__bf16)vq[h8*2+1].w;
            *(v8bf*)&xtb[r][c][h8*8] = o;
        }
    }
    __syncthreads();

    // phase 2: per-pixel affine params (fp32-exact Srow; cos/sin via rsqrt)
    if (tid < npx) {
        float den = 0.f, crn = 0.f, ccn = 0.f;
#pragma unroll
        for (int i = 0; i < 7; i++)
#pragma unroll
            for (int j = 0; j < 7; j++) {
                float v = Srow[i][tid + j];
                den += v; crn += v*(float)i; ccn += v*(float)j;
            }
        float dt = den + EPSF;
        float cr = crn/dt - 3.0f;
        float cx = ccn/dt - 3.0f + EPSF;
        float r2 = cr*cr + cx*cx;
        float inv = r2 > 0.f ? rsqrtf(r2) : 0.f;
        float c = r2 > 0.f ? cx*inv : 1.0f;
        float s = cr*inv;
        const float scale = 1.0f + EPSF;
        float xo = (6.0f - (c*6.0f - s*6.0f))*0.5f;
        float yo = (6.0f - (s*6.0f + c*6.0f))*0.5f;
        pp[tid] = make_float4(c/scale, s/scale, xo/scale, yo/scale);
    }
    __syncthreads();

    // phase 3: one thread per (px,pos); 16 b128 LDS reads/item (bf16 corners)
    for (int e = tid; e < 400; e += 256) {
        int px = e & 15; int pos = e >> 4;
        if (px < npx) {
            int py = pos/5; int yy = py + 1; int xx = pos - py*5 + 1;
            float4 p = pp[px];
            float xin = p.x*(float)xx - p.y*(float)yy + p.z;
            float yin = p.y*(float)xx + p.x*(float)yy + p.w;
            float x0f = floorf(xin), y0f = floorf(yin);
            float wx1 = xin - x0f, wx0 = 1.0f - wx1;
            float wy1 = yin - y0f, wy0 = 1.0f - wy1;
            int ix0 = (int)x0f, iy0 = (int)y0f;
            int ix1 = ix0 + 1,  iy1 = iy0 + 1;

            const __bf16* bp[4]; float wgt[4];
            auto mkcorner = [&](int yi, int xi, float w, int idx) {
                bool valid = (xi >= 0) & (xi < 7) & (yi >= 0) & (yi < 7);
                int cy = yi < 0 ? 0 : (yi > 6 ? 6 : yi);
                int cx2 = xi < 0 ? 0 : (xi > 6 ? 6 : xi);
                bp[idx]  = &xtb[cy][px + cx2][0];
                wgt[idx] = valid ? w : 0.0f;
            };
            mkcorner(iy0, ix0, wy0*wx0, 0);
            mkcorner(iy0, ix1, wy0*wx1, 1);
            mkcorner(iy1, ix0, wy1*wx0, 2);
            mkcorner(iy1, ix1, wy1*wx1, 3);

            float accx[16], accy[16];   // ch pairs (2i, 2i+1)
#pragma unroll
            for (int i = 0; i < 16; i++) { accx[i] = 0.f; accy[i] = 0.f; }
#pragma unroll
            for (int cn = 0; cn < 4; cn++) {
                const __bf16* src = bp[cn]; float wq = wgt[cn];
#pragma unroll
                for (int q8 = 0; q8 < 4; q8++) {
                    union { v8bf v; unsigned u[4]; } uv;
                    uv.v = *(const v8bf*)(src + q8*8);
#pragma unroll
                    for (int j = 0; j < 4; j++) {
                        float lo = __uint_as_float(uv.u[j] << 16);
                        float hi = __uint_as_float(uv.u[j] & 0xffff0000u);
                        accx[q8*4+j] += wq*lo;
                        accy[q8*4+j] += wq*hi;
                    }
                }
            }
#pragma unroll
            for (int q8 = 0; q8 < 4; q8++) {
                v8bf o;
#pragma unroll
                for (int j = 0; j < 4; j++) {
                    o[2*j]   = (__bf16)accx[q8*4+j];
                    o[2*j+1] = (__bf16)accy[q8*4+j];
                }
                *(v8bf*)&rot[px][pos*32 + q8*8] = o;
            }
        }
    }

    // first half of B-fragments: issue before barrier, latency hides under it
    const v8bf* wp = Wp + (size_t)wv*25*64 + lane;
    v8bf bfA[13];
#pragma unroll
    for (int kb = 0; kb < 13; kb++) bfA[kb] = wp[kb*64];
    __syncthreads();

    // phase 4: MFMA 16 px x 16 filters per wave, K=800.
    // Two independent acc chains (kb 0..12 / 13..24) -> issue-bound not
    // latency-bound; summed at the end.
    v8bf bfB[12];
#pragma unroll
    for (int kb = 0; kb < 12; kb++) bfB[kb] = wp[(13 + kb)*64];

    v4f acc0 = {0.f, 0.f, 0.f, 0.f};
    v4f acc1 = {0.f, 0.f, 0.f, 0.f};
#pragma unroll
    for (int kb = 0; kb < 12; kb++) {
        v8bf a0 = *(const v8bf*)&rot[m][kb*32 + q*8];
        acc0 = __builtin_amdgcn_mfma_f32_16x16x32_bf16(a0, bfA[kb], acc0, 0, 0, 0);
        v8bf a1 = *(const v8bf*)&rot[m][(13 + kb)*32 + q*8];
        acc1 = __builtin_amdgcn_mfma_f32_16x16x32_bf16(a1, bfB[kb], acc1, 0, 0, 0);
    }
    {
        v8bf a0 = *(const v8bf*)&rot[m][12*32 + q*8];
        acc0 = __builtin_amdgcn_mfma_f32_16x16x32_bf16(a0, bfA[12], acc0, 0, 0, 0);
    }

    int f = wv*16 + m;          // C/D col = lane&15 -> filter
    int pixbase = (b*HO + ho)*WO + wo0;
#pragma unroll
    for (int r = 0; r < 4; r++) {
        int px = q*4 + r;       // C/D row = (lane>>4)*4 + reg -> pixel
        if (px < npx) out[(size_t)(pixbase + px)*NF + f] = acc0[r] + acc1[r] + bv;
    }
}

extern "C" void kernel_launch(void* const* d_in, const int* in_sizes, int n_in,
                              void* d_out, int out_size, void* d_ws, size_t ws_size,
                              hipStream_t stream) {
    const float* x    = (const float*)d_in[0];
    const float* W    = (const float*)d_in[1];
    const float* bias = (const float*)d_in[2];
    float* out = (float*)d_out;
    __bf16* Wp = (__bf16*)d_ws;                    // 102,400 B

    k_wpack<<<dim3(200), 256, 0, stream>>>(W, Wp);
    k_main<<<dim3(4, HO, B_), 256, 0, stream>>>(x, (const v8bf*)Wp, bias, out);
}

// Round 7
// 76.167 us; speedup vs baseline: 1.9033x; 1.0280x over previous
//
#include <hip/hip_runtime.h>
#include <hip/hip_bf16.h>

#define EPSF 1e-7f
#define B_ 8
#define H_ 64
#define W_ 64
#define C_ 32
#define HO 58
#define WO 58
#define NF 64
#define KDIM 800

#define XBS 40      // xtb col stride (bf16): 80B -> +20 banks per col, b128-aligned
#define RS  808     // rot row stride (bf16): 1616B -> +20 banks per row, <=2-way (free)

typedef __bf16 v8bf __attribute__((ext_vector_type(8)));
typedef float  v4f  __attribute__((ext_vector_type(4)));
typedef float  v2f  __attribute__((ext_vector_type(2)));

// ---- pack W into MFMA B-fragment order, bf16 ----
// Wp[((nt*25+kb)*64+lane)*8+j] = W[f=nt*16+(lane&15)][k=kb*32+(lane>>4)*8+j]
__global__ void k_wpack(const float* __restrict__ W, __bf16* __restrict__ Wp) {
    int t = blockIdx.x*256 + threadIdx.x;   // 51200 total
    int j = t & 7; int lane = (t >> 3) & 63; int rest = t >> 9;
    int kb = rest % 25; int nt = rest / 25;
    int f = nt*16 + (lane & 15);
    int k = kb*32 + (lane >> 4)*8 + j;
    Wp[t] = (__bf16)W[f*KDIM + k];
}

// ---- fused: stage(bf16)+chansum -> angle(in-reg, wave-parallel) -> rotate -> MFMA ----
__global__ __launch_bounds__(256, 4)
void k_main(const float* __restrict__ x, const v8bf* __restrict__ Wp,
            const float* __restrict__ bias, float* __restrict__ out) {
    __shared__ __bf16 xtb[7][22][XBS];    // 12,320 B
    __shared__ __bf16 rot[16][RS];        // 25,856 B
    __shared__ float  Srow[7][22];        //    616 B   -> ~38.8 KB

    int tid = threadIdx.x;
    int wv = tid >> 6, lane = tid & 63;
    int m = lane & 15, q = lane >> 4;

    // XCD-aware remap: one batch b per XCD (x-slice 524 KB -> L2-resident).
    int L = blockIdx.x + 4*(blockIdx.y + 58*blockIdx.z);
    int newL = (L & 7)*232 + (L >> 3);
    int b  = newL / 232;
    int rem = newL - b*232;
    int ho = rem >> 2;
    int wt = rem & 3;

    int wo0 = wt*16;
    int npx = WO - wo0; if (npx > 16) npx = 16;   // 16,16,16,10
    int ncols = npx + 6;                          // 22 or 16

    float bv = bias[wv*16 + m];                   // hoisted off the tail

    // phase 0+1: one thread per (r,c): load 32 fp32 ch, exact fp32 sum -> Srow,
    // bf16 round -> xtb. One barrier covers both.
    if (tid < 7*ncols) {
        int r, c;
        if (ncols == 22) { r = tid/22; c = tid - r*22; }
        else             { r = tid >> 4; c = tid & 15; }
        const float* src = x + (size_t)((b*H_ + ho + r)*W_ + wo0 + c)*C_;
        float4 vq[8];
#pragma unroll
        for (int qq = 0; qq < 8; qq++) vq[qq] = *(const float4*)(src + qq*4);
        float s = 0.f;
#pragma unroll
        for (int qq = 0; qq < 8; qq++) s += vq[qq].x + vq[qq].y + vq[qq].z + vq[qq].w;
        Srow[r][c] = s;
#pragma unroll
        for (int h8 = 0; h8 < 4; h8++) {
            v8bf o;
            o[0]=(__bf16)vq[h8*2].x;   o[1]=(__bf16)vq[h8*2].y;
            o[2]=(__bf16)vq[h8*2].z;   o[3]=(__bf16)vq[h8*2].w;
            o[4]=(__bf16)vq[h8*2+1].x; o[5]=(__bf16)vq[h8*2+1].y;
            o[6]=(__bf16)vq[h8*2+1].z; o[7]=(__bf16)vq[h8*2+1].w;
            *(v8bf*)&xtb[r][c][h8*8] = o;
        }
    }
    __syncthreads();

    // phase 2 (wave-parallel, in-register): lane owns pxl = 4*wv + q; the 16
    // lanes per pixel (slot = m) split the 49 window terms, shfl_xor reduce.
    int pxl = wv*4 + q;
    float den = 0.f, crn = 0.f, ccn = 0.f;
#pragma unroll
    for (int k = 0; k < 4; k++) {
        int t = m + 16*k;
        if (t < 49) {
            int i = t / 7, j = t - 7*i;
            float v = Srow[i][pxl + j];
            den += v; crn += v*(float)i; ccn += v*(float)j;
        }
    }
#pragma unroll
    for (int msk = 1; msk <= 8; msk <<= 1) {
        den += __shfl_xor(den, msk);
        crn += __shfl_xor(crn, msk);
        ccn += __shfl_xor(ccn, msk);
    }
    float pc, ps, pxo, pyo;
    {
        float dt = den + EPSF;
        float cr = crn/dt - 3.0f;
        float cx = ccn/dt - 3.0f + EPSF;
        float r2 = cr*cr + cx*cx;
        float inv = r2 > 0.f ? rsqrtf(r2) : 0.f;
        float c = r2 > 0.f ? cx*inv : 1.0f;
        float s = cr*inv;
        const float scale = 1.0f + EPSF;
        pc  = c/scale; ps = s/scale;
        pxo = (6.0f - (c*6.0f - s*6.0f))*0.5f/scale;
        pyo = (6.0f - (s*6.0f + c*6.0f))*0.5f/scale;
    }

    // phase 3 (in-wave): wave wv covers px 4wv..4wv+3; pos = m + 16*rnd.
    // 2 uniform rounds per wave -> zero barrier skew. Packed fp32 FMA core.
#pragma unroll
    for (int rnd = 0; rnd < 2; rnd++) {
        int pos = m + 16*rnd;
        if (pos < 25) {
            int py = pos/5; int yy = py + 1; int xx = pos - py*5 + 1;
            float xin = pc*(float)xx - ps*(float)yy + pxo;
            float yin = ps*(float)xx + pc*(float)yy + pyo;
            float x0f = floorf(xin), y0f = floorf(yin);
            float wx1 = xin - x0f, wx0 = 1.0f - wx1;
            float wy1 = yin - y0f, wy0 = 1.0f - wy1;
            int ix0 = (int)x0f, iy0 = (int)y0f;
            int ix1 = ix0 + 1,  iy1 = iy0 + 1;

            const __bf16* bp[4]; float wgt[4];
            auto mkcorner = [&](int yi, int xi, float w, int idx) {
                bool valid = (xi >= 0) & (xi < 7) & (yi >= 0) & (yi < 7);
                int cy = yi < 0 ? 0 : (yi > 6 ? 6 : yi);
                int cx2 = xi < 0 ? 0 : (xi > 6 ? 6 : xi);
                bp[idx]  = &xtb[cy][pxl + cx2][0];
                wgt[idx] = valid ? w : 0.0f;
            };
            mkcorner(iy0, ix0, wy0*wx0, 0);
            mkcorner(iy0, ix1, wy0*wx1, 1);
            mkcorner(iy1, ix0, wy1*wx0, 2);
            mkcorner(iy1, ix1, wy1*wx1, 3);

            v2f acc[16];   // acc[i] = channels (2i, 2i+1)
#pragma unroll
            for (int i = 0; i < 16; i++) acc[i] = (v2f){0.f, 0.f};
#pragma unroll
            for (int cn = 0; cn < 4; cn++) {
                const __bf16* src = bp[cn];
                v2f wq2 = (v2f){wgt[cn], wgt[cn]};
#pragma unroll
                for (int q8 = 0; q8 < 4; q8++) {
                    union { v8bf v; unsigned u[4]; } uv;
                    uv.v = *(const v8bf*)(src + q8*8);
#pragma unroll
                    for (int d = 0; d < 4; d++) {
                        v2f val = (v2f){ __uint_as_float(uv.u[d] << 16),
                                         __uint_as_float(uv.u[d] & 0xffff0000u) };
                        acc[q8*4 + d] += wq2 * val;   // v_pk_fma_f32
                    }
                }
            }
#pragma unroll
            for (int q8 = 0; q8 < 4; q8++) {
                v8bf o;
#pragma unroll
                for (int d = 0; d < 4; d++) {
                    o[2*d]   = (__bf16)acc[q8*4 + d].x;
                    o[2*d+1] = (__bf16)acc[q8*4 + d].y;
                }
                *(v8bf*)&rot[pxl][pos*32 + q8*8] = o;
            }
        }
    }

    // first half of B-fragments: issue before barrier, latency hides under it
    const v8bf* wp = Wp + (size_t)wv*25*64 + lane;
    v8bf bfA[13];
#pragma unroll
    for (int kb = 0; kb < 13; kb++) bfA[kb] = wp[kb*64];
    __syncthreads();

    // phase 4: MFMA 16 px x 16 filters per wave, K=800; dual acc chains.
    v8bf bfB[12];
#pragma unroll
    for (int kb = 0; kb < 12; kb++) bfB[kb] = wp[(13 + kb)*64];

    v4f acc0 = {0.f, 0.f, 0.f, 0.f};
    v4f acc1 = {0.f, 0.f, 0.f, 0.f};
#pragma unroll
    for (int kb = 0; kb < 12; kb++) {
        v8bf a0 = *(const v8bf*)&rot[m][kb*32 + q*8];
        acc0 = __builtin_amdgcn_mfma_f32_16x16x32_bf16(a0, bfA[kb], acc0, 0, 0, 0);
        v8bf a1 = *(const v8bf*)&rot[m][(13 + kb)*32 + q*8];
        acc1 = __builtin_amdgcn_mfma_f32_16x16x32_bf16(a1, bfB[kb], acc1, 0, 0, 0);
    }
    {
        v8bf a0 = *(const v8bf*)&rot[m][12*32 + q*8];
        acc0 = __builtin_amdgcn_mfma_f32_16x16x32_bf16(a0, bfA[12], acc0, 0, 0, 0);
    }

    int f = wv*16 + m;          // C/D col = lane&15 -> filter
    int pixbase = (b*HO + ho)*WO + wo0;
#pragma unroll
    for (int r = 0; r < 4; r++) {
        int px = q*4 + r;       // C/D row = (lane>>4)*4 + reg -> pixel
        if (px < npx) out[(size_t)(pixbase + px)*NF + f] = acc0[r] + acc1[r] + bv;
    }
}

extern "C" void kernel_launch(void* const* d_in, const int* in_sizes, int n_in,
                              void* d_out, int out_size, void* d_ws, size_t ws_size,
                              hipStream_t stream) {
    const float* x    = (const float*)d_in[0];
    const float* W    = (const float*)d_in[1];
    const float* bias = (const float*)d_in[2];
    float* out = (float*)d_out;
    __bf16* Wp = (__bf16*)d_ws;                    // 102,400 B

    k_wpack<<<dim3(200), 256, 0, stream>>>(W, Wp);
    k_main<<<dim3(4, HO, B_), 256, 0, stream>>>(x, (const v8bf*)Wp, bias, out);
}